// Round 17
// baseline (302.542 us; speedup 1.0000x reference)
//
#include <hip/hip_runtime.h>

// ---------------------------------------------------------------------------
// SemanticMemoryLatentSpace, fully factored (see R7 header).
// R16: wave0 = pure decision chain (NO DS writes, NO global loads in main
// loop). Wave1 applies all RAW updates (same order -> bitwise identical),
// wave0 self-patches one round deep via 16-diagonal gx table and reads
// columns mid-round gated by wave1's progress flag (always ahead).
// ---------------------------------------------------------------------------

#define A_BOOSTF 0.012247448713915891f // 1.5*alpha (growth==0 always)

template <int CTRL>
__device__ __forceinline__ float dpp_f(float x) {
  return __int_as_float(
      __builtin_amdgcn_mov_dpp(__float_as_int(x), CTRL, 0xf, 0xf, true));
}
template <int CTRL>
__device__ __forceinline__ unsigned dpp_u(unsigned x) {
  return (unsigned)__builtin_amdgcn_mov_dpp((int)x, CTRL, 0xf, 0xf, true);
}
__device__ __forceinline__ float rdlane_f(float x, int l) {
  return __int_as_float(__builtin_amdgcn_readlane(__float_as_int(x), l));
}
__device__ __forceinline__ unsigned rdlane_u(unsigned x, int l) {
  return (unsigned)__builtin_amdgcn_readlane((int)x, l);
}
__device__ __forceinline__ float wave_sum64(float v) {
  v += dpp_f<0xB1>(v);
  v += dpp_f<0x4E>(v);
  v += dpp_f<0x124>(v);
  v += dpp_f<0x128>(v);
  return (rdlane_f(v, 0) + rdlane_f(v, 16)) + (rdlane_f(v, 32) + rdlane_f(v, 48));
}
__device__ __forceinline__ unsigned sortable(float v) {
  unsigned u = __float_as_uint(v);
  return u ^ (unsigned)(((int)u >> 31) | 0x80000000);
}
__device__ __forceinline__ float unsortable(unsigned x) {
  unsigned u = (x & 0x80000000u) ? (x ^ 0x80000000u) : ~x;
  return __uint_as_float(u);
}
__device__ __forceinline__ unsigned wave_umax64(unsigned v) {
  v = max(v, dpp_u<0xB1>(v));
  v = max(v, dpp_u<0x4E>(v));
  v = max(v, dpp_u<0x124>(v));
  v = max(v, dpp_u<0x128>(v));
  return max(max(rdlane_u(v, 0), rdlane_u(v, 16)),
             max(rdlane_u(v, 32), rdlane_u(v, 48)));
}

// compile-time component select from gxq[K][4xfloat4] for diagonal D (0..15)
#define GXC(K, D)                                                              \
  ((D) < 4 ? ((D) == 0   ? gxq[K][0].x                                         \
              : (D) == 1 ? gxq[K][0].y                                         \
              : (D) == 2 ? gxq[K][0].z                                         \
                         : gxq[K][0].w)                                        \
   : (D) < 8                                                                   \
       ? ((D) == 4   ? gxq[K][1].x                                             \
          : (D) == 5 ? gxq[K][1].y                                             \
          : (D) == 6 ? gxq[K][1].z                                             \
                     : gxq[K][1].w)                                            \
   : (D) < 12 ? ((D) == 8    ? gxq[K][2].x                                     \
                 : (D) == 9  ? gxq[K][2].y                                     \
                 : (D) == 10 ? gxq[K][2].z                                     \
                             : gxq[K][2].w)                                    \
              : ((D) == 12   ? gxq[K][3].x                                     \
                 : (D) == 13 ? gxq[K][3].y                                     \
                 : (D) == 14 ? gxq[K][3].z                                     \
                             : gxq[K][3].w))

// ---------------- generic 32x32-tile fp32 GEMMs -----------------------------
__global__ __launch_bounds__(256) void gemm_nt(const float* __restrict__ A,
                                               const float* __restrict__ B,
                                               float* __restrict__ C,
                                               int N, int K) {
  __shared__ float As[32][33];
  __shared__ float Bs[32][33];
  int bx = blockIdx.x, by = blockIdx.y;
  int tid = threadIdx.x;
  int tx = tid & 15, ty = tid >> 4;
  float a00 = 0.f, a01 = 0.f, a10 = 0.f, a11 = 0.f;
  for (int k0 = 0; k0 < K; k0 += 32) {
    for (int l = tid; l < 1024; l += 256) {
      int r = l >> 5, c = l & 31;
      As[r][c] = A[(by * 32 + r) * K + k0 + c];
      Bs[r][c] = B[(bx * 32 + r) * K + k0 + c];
    }
    __syncthreads();
#pragma unroll
    for (int k = 0; k < 32; ++k) {
      float x0 = As[2 * ty][k], x1 = As[2 * ty + 1][k];
      float y0 = Bs[2 * tx][k], y1 = Bs[2 * tx + 1][k];
      a00 += x0 * y0; a01 += x0 * y1; a10 += x1 * y0; a11 += x1 * y1;
    }
    __syncthreads();
  }
  int i = by * 32 + 2 * ty, jj = bx * 32 + 2 * tx;
  C[i * N + jj] = a00;           C[i * N + jj + 1] = a01;
  C[(i + 1) * N + jj] = a10;     C[(i + 1) * N + jj + 1] = a11;
}

__global__ __launch_bounds__(256) void gemm_nn(const float* __restrict__ A,
                                               const float* __restrict__ B,
                                               float* __restrict__ C,
                                               int N, int K) {
  __shared__ float As[32][33];
  __shared__ float Bs[32][33];
  int bx = blockIdx.x, by = blockIdx.y;
  int tid = threadIdx.x;
  int tx = tid & 15, ty = tid >> 4;
  float a00 = 0.f, a01 = 0.f, a10 = 0.f, a11 = 0.f;
  for (int k0 = 0; k0 < K; k0 += 32) {
    for (int l = tid; l < 1024; l += 256) {
      int r = l >> 5, c = l & 31;
      As[r][c] = A[(by * 32 + r) * K + k0 + c];
      Bs[r][c] = B[(k0 + r) * N + bx * 32 + c];
    }
    __syncthreads();
#pragma unroll
    for (int k = 0; k < 32; ++k) {
      float x0 = As[2 * ty][k], x1 = As[2 * ty + 1][k];
      float y0 = Bs[k][2 * tx], y1 = Bs[k][2 * tx + 1];
      a00 += x0 * y0; a01 += x0 * y1; a10 += x1 * y0; a11 += x1 * y1;
    }
    __syncthreads();
  }
  int i = by * 32 + 2 * ty, jj = bx * 32 + 2 * tx;
  C[i * N + jj] = a00;           C[i * N + jj + 1] = a01;
  C[(i + 1) * N + jj] = a10;     C[(i + 1) * N + jj + 1] = a11;
}

__global__ __launch_bounds__(256) void final_gemm(const float* __restrict__ G,
                                                  const float* __restrict__ E,
                                                  const float* __restrict__ M0,
                                                  const float* __restrict__ W,
                                                  const float* __restrict__ gS,
                                                  float* __restrict__ out) {
  __shared__ float As[32][33];
  __shared__ float Bs[32][33];
  int bx = blockIdx.x, by = blockIdx.y;
  int tid = threadIdx.x;
  int tx = tid & 15, ty = tid >> 4;
  float a00 = 0.f, a01 = 0.f, a10 = 0.f, a11 = 0.f;
  for (int k0 = 0; k0 < 512; k0 += 32) {
    for (int l = tid; l < 1024; l += 256) {
      int r = l >> 5, c = l & 31;
      As[r][c] = G[(by * 32 + r) * 512 + k0 + c] * W[k0 + c];
      Bs[r][c] = E[(k0 + r) * 384 + bx * 32 + c];
    }
    __syncthreads();
#pragma unroll
    for (int k = 0; k < 32; ++k) {
      float x0 = As[2 * ty][k], x1 = As[2 * ty + 1][k];
      float y0 = Bs[k][2 * tx], y1 = Bs[k][2 * tx + 1];
      a00 += x0 * y0; a01 += x0 * y1; a10 += x1 * y0; a11 += x1 * y1;
    }
    __syncthreads();
  }
  float gv = gS[0];
  int i = by * 32 + 2 * ty, jj = bx * 32 + 2 * tx;
  out[i * 384 + jj]         = gv * M0[i * 384 + jj]         + a00;
  out[i * 384 + jj + 1]     = gv * M0[i * 384 + jj + 1]     + a01;
  out[(i + 1) * 384 + jj]     = gv * M0[(i + 1) * 384 + jj]     + a10;
  out[(i + 1) * 384 + jj + 1] = gv * M0[(i + 1) * 384 + jj + 1] + a11;
}

__global__ __launch_bounds__(256) void prep_kernel(const float* __restrict__ E,
                                                   const float* __restrict__ M0,
                                                   const float* __restrict__ K0,
                                                   float* __restrict__ u,
                                                   float* __restrict__ Kpart) {
  __shared__ double wr[4];
  int b = blockIdx.x;
  int tid = threadIdx.x, lane = tid & 63, wv = tid >> 6;
  if (b < 128) {
    int row = b * 4 + wv;
    const float4* e4 = (const float4*)(E + row * 384);
    const float4* m4 = (const float4*)(M0 + row * 384);
    float p = 0.f;
    for (int i = lane; i < 96; i += 64) {
      float4 a = e4[i], bb = m4[i];
      p += a.x * bb.x + a.y * bb.y + a.z * bb.z + a.w * bb.w;
    }
#pragma unroll
    for (int off = 32; off; off >>= 1) p += __shfl_down(p, off);
    if (lane == 0) u[row] = p;
  } else {
    int cb = b - 128;
    const float* p = K0 + cb * 2304 + tid * 9;
    double acc = 0.0;
#pragma unroll
    for (int i = 0; i < 9; ++i) { double v = (double)p[i]; acc += v * v; }
#pragma unroll
    for (int off = 32; off; off >>= 1) acc += __shfl_down(acc, off);
    if (lane == 0) wr[wv] = acc;
    __syncthreads();
    if (tid == 0) Kpart[cb] = (float)(wr[0] + wr[1] + wr[2] + wr[3]);
  }
}

// ---------------- decoupled two-wave scan, wave0 = chain only ---------------
__global__ __launch_bounds__(128) void scan_kernel(const float* __restrict__ G,
                                                   const float* __restrict__ u,
                                                   const float* __restrict__ Kpart,
                                                   float* __restrict__ Wout,
                                                   float* __restrict__ gOut) {
  __shared__ float RAW[100 * 257];      // 102800 B
  __shared__ float gx_tbl[512 * 16];    // [t][d]: G[t][t+d], d=0..15 (32768 B)
  __shared__ float ren_tbl[512];
  __shared__ float u_sh[512];
  __shared__ float wh_sh[512];
  __shared__ float4 RING[512];          // {bnew, idxbits, nov, 0}
  __shared__ int FLAG;                  // rounds published by wave0
  __shared__ int FLAG2;                 // last round applied to RAW by wave1

  const int tid = threadIdx.x;
  const int wid = tid >> 6;
  const int lane = tid & 63;

  // ---- cooperative init ----
  float4 z4 = {0.f, 0.f, 0.f, 0.f};
  for (int i = tid; i < 6425; i += 128) ((float4*)RAW)[i] = z4;
  for (int tt = tid; tt < 512; tt += 128) {
    const float* gr = G + tt * 512 + tt;
    const int lim = 512 - tt;
#pragma unroll
    for (int d = 0; d < 16; ++d)
      gx_tbl[tt * 16 + d] = (d < lim) ? gr[d] : 0.f;
    ren_tbl[tt] = __builtin_amdgcn_rcpf(__builtin_amdgcn_sqrtf(gr[0]));
  }
  if (tid < 128) ((float4*)u_sh)[tid] = ((const float4*)u)[tid];
  if (tid == 0) { FLAG = 0; FLAG2 = -1; }
  __syncthreads();

  if (wid == 0) {
    // ================== WAVE 0: decision chain only ==================
    float d0 = 1.f, d1 = 1.f, cn0 = 0.f, cn1 = 0.f, s0 = 0.f, s1 = 0.f;
    int nact = 0;
    float r0[8], r1[8];
#pragma unroll
    for (int j = 0; j < 8; ++j) { r0[j] = 0.f; r1[j] = 0.f; }

#define W0STEP(K)                                                              \
    {                                                                          \
      float v0 = (lane < nact) ? s0 * renk[K] * r0[K] : -2.f;                  \
      float v1 = (lane + 64 < nact) ? s1 * renk[K] * r1[K] : -2.f;             \
      unsigned pk0 = (sortable(v0) & ~127u) | (unsigned)(127 - lane);          \
      unsigned pk1 = (sortable(v1) & ~127u) | (unsigned)(63 - lane);           \
      unsigned P = wave_umax64(max(pk0, pk1));                                 \
      int imax = 127 - (int)(P & 127u);                                        \
      float M = unsortable(P & ~127u);                                         \
      float nov = (nact == 0) ? 1.f : fminf(1.f, fmaxf(0.f, 1.f - M * M));     \
      int create = (nov > 0.7f && nact < 100) ? 1 : 0;                         \
      const int idxs = create ? nact : imax;                                   \
      const int cl = idxs & 63, hi = idxs >> 6;                                \
      float dcA = create ? 1.f : 0.95f * d0;                                   \
      float dcB = create ? 1.f : 0.95f * d1;                                   \
      float ccA = create ? trk[K]                                              \
                         : (0.9025f * cn0 + 0.095f * (d0 * r0[K]) +            \
                            0.0025f * trk[K]);                                 \
      float ccB = create ? trk[K]                                              \
                         : (0.9025f * cn1 + 0.095f * (d1 * r1[K]) +            \
                            0.0025f * trk[K]);                                 \
      float scA = dcA * __builtin_amdgcn_rcpf(__builtin_amdgcn_sqrtf(ccA));    \
      float scB = dcB * __builtin_amdgcn_rcpf(__builtin_amdgcn_sqrtf(ccB));    \
      float ivA = 0.05f * __builtin_amdgcn_rcpf(dcA);                          \
      float ivB = 0.05f * __builtin_amdgcn_rcpf(dcB);                          \
      bool own0 = (lane == cl) && (hi == 0);                                   \
      bool own1 = (lane == cl) && (hi == 1);                                   \
      d0 = own0 ? dcA : d0; cn0 = own0 ? ccA : cn0; s0 = own0 ? scA : s0;      \
      d1 = own1 ? dcB : d1; cn1 = own1 ? ccB : cn1; s1 = own1 ? scB : s1;      \
      float bnew = create ? 1.f : rdlane_f(hi ? ivB : ivA, cl);                \
      nact += create;                                                          \
      float pb0 = own0 ? bnew : 0.f, pb1 = own1 ? bnew : 0.f;                  \
      _Pragma("unroll") for (int j = (K) + 1; j < 8; ++j) {                    \
        r0[j] += pb0 * GXC(K, (j) - (K));                                      \
        r1[j] += pb1 * GXC(K, (j) - (K));                                      \
      }                                                                        \
      bnewA[K] = bnew; novA[K] = nov; idxA[K] = idxs;                          \
      pb0A[K] = pb0; pb1A[K] = pb1;                                            \
    }

    for (int R = 0; R < 64; ++R) {
      const int t = 8 * R;
      const int c = t & 255;
      const int tn = t + 8;
      const int cnx = tn & 255;

      if (t == 256) {
        // ---- rebuild block 2 (cols 256..511) from RING, steps 0..255 ----
        while (__hip_atomic_load(&FLAG2, __ATOMIC_ACQUIRE,
                                 __HIP_MEMORY_SCOPE_WORKGROUP) < 31)
          __builtin_amdgcn_s_sleep(1);
        for (int i = lane; i < 6425; i += 64) ((float4*)RAW)[i] = z4;
        __builtin_amdgcn_sched_barrier(0);
        const float* Gb = G + 256;
        float A[4][4], Bv[4][4];
        float4 SA[4], SB[4];
#pragma unroll
        for (int j = 0; j < 4; ++j) {
#pragma unroll
          for (int m = 0; m < 4; ++m) A[j][m] = Gb[j * 512 + m * 64 + lane];
          SA[j] = RING[j];
        }
        for (int s = 0; s < 256; s += 8) {
#pragma unroll
          for (int j = 0; j < 4; ++j) {
#pragma unroll
            for (int m = 0; m < 4; ++m)
              Bv[j][m] = Gb[(s + 4 + j) * 512 + m * 64 + lane];
            SB[j] = RING[s + 4 + j];
          }
#pragma unroll
          for (int j = 0; j < 4; ++j) {
            float bh = SA[j].x; int id = __float_as_int(SA[j].y);
#pragma unroll
            for (int m = 0; m < 4; ++m) {
              const int a_ = id * 257 + m * 64 + lane;
              RAW[a_] += bh * A[j][m];
            }
          }
          if (s + 8 < 256) {
#pragma unroll
            for (int j = 0; j < 4; ++j) {
#pragma unroll
              for (int m = 0; m < 4; ++m)
                A[j][m] = Gb[(s + 8 + j) * 512 + m * 64 + lane];
              SA[j] = RING[s + 8 + j];
            }
          }
#pragma unroll
          for (int j = 0; j < 4; ++j) {
            float bh = SB[j].x; int id = __float_as_int(SB[j].y);
#pragma unroll
            for (int m = 0; m < 4; ++m) {
              const int a_ = id * 257 + m * 64 + lane;
              RAW[a_] += bh * Bv[j][m];
            }
          }
        }
        __builtin_amdgcn_sched_barrier(0);
#pragma unroll
        for (int j = 0; j < 8; ++j) r0[j] = RAW[lane * 257 + j];
        if (lane < 36) {
#pragma unroll
          for (int j = 0; j < 8; ++j) r1[j] = RAW[(lane + 64) * 257 + j];
        }
        __builtin_amdgcn_sched_barrier(0);
      }

      // per-round diagonals (LDS, off-chain)
      float4 gxq[8][4];
      float trk[8], renk[8];
#pragma unroll
      for (int k = 0; k < 8; ++k) {
        const float4* gp = (const float4*)(gx_tbl + (t + k) * 16);
        gxq[k][0] = gp[0]; gxq[k][1] = gp[1];
        gxq[k][2] = gp[2]; gxq[k][3] = gp[3];
        trk[k] = gxq[k][0].x;
        renk[k] = ren_tbl[t + k];
      }

      float bnewA[8], novA[8], pb0A[8], pb1A[8];
      int idxA[8];

      W0STEP(0) W0STEP(1) W0STEP(2) W0STEP(3)

      // mid-round: wait for wave1 progress, issue next-round column reads
      float r0n[8], r1n[8];
      const bool doRead = (tn < 512) && (cnx != 0);
      if (doRead) {
        while (__hip_atomic_load(&FLAG2, __ATOMIC_ACQUIRE,
                                 __HIP_MEMORY_SCOPE_WORKGROUP) < R - 1)
          __builtin_amdgcn_s_sleep(1);
#pragma unroll
        for (int j = 0; j < 8; ++j) r0n[j] = RAW[lane * 257 + cnx + j];
        if (lane < 36) {
#pragma unroll
          for (int j = 0; j < 8; ++j) r1n[j] = RAW[(lane + 64) * 257 + cnx + j];
        } else {
#pragma unroll
          for (int j = 0; j < 8; ++j) r1n[j] = 0.f;
        }
      }

      W0STEP(4) W0STEP(5) W0STEP(6) W0STEP(7)

      // commit next-round r with self-patch of this round's decisions
      if (doRead) {
#pragma unroll
        for (int j = 0; j < 8; ++j) {
          float pa = 0.f, pb = 0.f;
#pragma unroll
          for (int k = 0; k < 8; ++k) {
            pa += pb0A[k] * GXC(k, 8 + (j) - (k));
            pb += pb1A[k] * GXC(k, 8 + (j) - (k));
          }
          r0[j] = r0n[j] + pa;
          r1[j] = r1n[j] + pb;
        }
      }

      // publish decisions (after reads; wave1 may then apply round R)
      if (lane == 0) {
#pragma unroll
        for (int k = 0; k < 8; ++k) {
          float4 r4; r4.x = bnewA[k]; r4.y = __int_as_float(idxA[k]);
          r4.z = novA[k]; r4.w = 0.f;
          RING[t + k] = r4;
        }
        __hip_atomic_store(&FLAG, R + 1, __ATOMIC_RELEASE,
                           __HIP_MEMORY_SCOPE_WORKGROUP);
      }
    }
#undef W0STEP
  } else {
    // ================== WAVE 1: RAW apply + lag ==================
    float q8[8];
#pragma unroll
    for (int gI = 0; gI < 8; ++gI) q8[gI] = 0.f;
    float n2 = wave_sum64(Kpart[lane]);
    float g = 1.f, ginv = 1.f;

    for (int r = 0; r < 64; ++r) {
      const int t = 8 * r;
      const int c = t & 255;
      const int gbase = (t >> 6) & ~3;   // 0 for block1, 4 for block2

      // issue this round's G-row loads early
      float B[8][8];
#pragma unroll
      for (int k = 0; k < 8; ++k)
#pragma unroll
        for (int gI = 0; gI < 8; ++gI)
          B[k][gI] = G[(t + k) * 512 + gI * 64 + lane];

      while (__hip_atomic_load(&FLAG, __ATOMIC_ACQUIRE,
                               __HIP_MEMORY_SCOPE_WORKGROUP) < r + 1)
        __builtin_amdgcn_s_sleep(1);

      float4 rgv[8];
#pragma unroll
      for (int k = 0; k < 8; ++k) rgv[k] = RING[t + k];

      // RAW apply: same step/group order as original -> bitwise identical
#pragma unroll
      for (int k = 0; k < 8; ++k) {
        float bnew = rgv[k].x;
        int id = __float_as_int(rgv[k].y);
#pragma unroll
        for (int mg = 0; mg < 4; ++mg)
          if (mg * 64 + 63 >= c) {
            const int a_ = id * 257 + mg * 64 + lane;
            RAW[a_] += bnew * B[k][gbase + mg];
          }
      }
      __hip_atomic_store(&FLAG2, r, __ATOMIC_RELEASE,
                         __HIP_MEMORY_SCOPE_WORKGROUP);

      // lag chain
      float trm[8], gxw[8][8];
#pragma unroll
      for (int m = 0; m < 8; ++m) {
        trm[m] = gx_tbl[(t + m) * 16];
#pragma unroll
        for (int j = m + 1; j < 8; ++j)
          gxw[m][j] = gx_tbl[(t + m) * 16 + (j - m)];
      }
      float4 uuA = *(const float4*)&u_sh[t];
      float4 uuB = *(const float4*)&u_sh[t + 4];
      float um[8] = {uuA.x, uuA.y, uuA.z, uuA.w, uuB.x, uuB.y, uuB.z, uuB.w};

      const int grp = t >> 6;
      float qsel = q8[0];
#pragma unroll
      for (int gI = 1; gI < 8; ++gI) qsel = (grp == gI) ? q8[gI] : qsel;
      float qeff[8];
#pragma unroll
      for (int k = 0; k < 8; ++k) qeff[k] = rdlane_f(qsel, (t & 63) + k);

      float wh[8];
#pragma unroll
      for (int m = 0; m < 8; ++m) {
        float nov = rgv[m].z;
        float iw = nov * __builtin_amdgcn_sqrtf(nov);
        float psc = 384.0f * __builtin_amdgcn_rcpf(fmaxf(trm[m], 1e-8f));
        float ccf = A_BOOSTF * iw * psc;
        float qv = g * (um[m] + qeff[m]);
        float n2n = n2 + 2.f * ccf * qv + ccf * ccf * trm[m] * trm[m];
        float kn = __builtin_amdgcn_sqrtf(n2n);
        float fct = (kn > 50.f) ? 50.f * __builtin_amdgcn_rcpf(kn) : 1.f;
        float fiv = (kn > 50.f) ? kn * 0.02f : 1.f;
        wh[m] = ccf * ginv;
        n2 = n2n * fct * fct; g *= fct; ginv *= fiv;
#pragma unroll
        for (int j = m + 1; j < 8; ++j)
          qeff[j] += wh[m] * gxw[m][j] * gxw[m][j];
      }

      if (lane == 0) {
#pragma unroll
        for (int m = 0; m < 8; ++m) wh_sh[t + m] = wh[m];
      }
#pragma unroll
      for (int gI = 0; gI < 8; ++gI)
#pragma unroll
        for (int k = 0; k < 8; ++k)
          q8[gI] += wh[k] * B[k][gI] * B[k][gI];
    }

    for (int s2 = lane; s2 < 512; s2 += 64) Wout[s2] = wh_sh[s2] * g;
    if (lane == 0) gOut[0] = g;
  }
}

extern "C" void kernel_launch(void* const* d_in, const int* in_sizes, int n_in,
                              void* d_out, int out_size, void* d_ws,
                              size_t ws_size, hipStream_t stream) {
  const float* E = (const float*)d_in[0];   // [512,384]
  const float* K0 = (const float*)d_in[1];  // [384,384]
  float* out = (float*)d_out;               // [512,384]

  float* G = (float*)d_ws;                  // 512*512
  float* M0 = G + 512 * 512;                // 512*384
  float* u = M0 + 512 * 384;                // 512
  float* W = u + 512;                       // 512
  float* gS = W + 512;                      // 1
  float* Kpart = gS + 1;                    // 64

  gemm_nt<<<dim3(16, 16), 256, 0, stream>>>(E, E, G, 512, 384);     // G = E E^T
  gemm_nn<<<dim3(12, 16), 256, 0, stream>>>(E, K0, M0, 384, 384);   // M0 = E K0
  prep_kernel<<<192, 256, 0, stream>>>(E, M0, K0, u, Kpart);
  scan_kernel<<<1, 128, 0, stream>>>(G, u, Kpart, W, gS);
  final_gemm<<<dim3(12, 16), 256, 0, stream>>>(G, E, M0, W, gS, out);
}

// Round 18
// 259.839 us; speedup vs baseline: 1.1643x; 1.1643x over previous
//
#include <hip/hip_runtime.h>

// ---------------------------------------------------------------------------
// SemanticMemoryLatentSpace, fully factored (see R7 header).
// R17: THREE-wave scan.
//   wave0: pure decision chain. No RMW, no global loads. gxq prefetch 1 step
//          ahead (LDS); next-round patch accumulated in-step; end-of-round
//          column reads gated on FLAG2>=R-1 (wave1 is always ahead), THEN
//          publish RING+FLAG (no-race invariant: RAW == rounds <= R-1).
//   wave1: RAW-apply only (32 global loads + 32 plain RMW per round; fast).
//   wave2: lag chain + q + wh (independent of RAW).
// Accumulation order preserved -> bitwise-identical output (absmax 0.125).
// ---------------------------------------------------------------------------

#define A_BOOSTF 0.012247448713915891f // 1.5*alpha (growth==0 always)

template <int CTRL>
__device__ __forceinline__ float dpp_f(float x) {
  return __int_as_float(
      __builtin_amdgcn_mov_dpp(__float_as_int(x), CTRL, 0xf, 0xf, true));
}
template <int CTRL>
__device__ __forceinline__ unsigned dpp_u(unsigned x) {
  return (unsigned)__builtin_amdgcn_mov_dpp((int)x, CTRL, 0xf, 0xf, true);
}
__device__ __forceinline__ float rdlane_f(float x, int l) {
  return __int_as_float(__builtin_amdgcn_readlane(__float_as_int(x), l));
}
__device__ __forceinline__ unsigned rdlane_u(unsigned x, int l) {
  return (unsigned)__builtin_amdgcn_readlane((int)x, l);
}
__device__ __forceinline__ float wave_sum64(float v) {
  v += dpp_f<0xB1>(v);
  v += dpp_f<0x4E>(v);
  v += dpp_f<0x124>(v);
  v += dpp_f<0x128>(v);
  return (rdlane_f(v, 0) + rdlane_f(v, 16)) + (rdlane_f(v, 32) + rdlane_f(v, 48));
}
__device__ __forceinline__ unsigned sortable(float v) {
  unsigned u = __float_as_uint(v);
  return u ^ (unsigned)(((int)u >> 31) | 0x80000000);
}
__device__ __forceinline__ float unsortable(unsigned x) {
  unsigned u = (x & 0x80000000u) ? (x ^ 0x80000000u) : ~x;
  return __uint_as_float(u);
}
__device__ __forceinline__ unsigned wave_umax64(unsigned v) {
  v = max(v, dpp_u<0xB1>(v));
  v = max(v, dpp_u<0x4E>(v));
  v = max(v, dpp_u<0x124>(v));
  v = max(v, dpp_u<0x128>(v));
  return max(max(rdlane_u(v, 0), rdlane_u(v, 16)),
             max(rdlane_u(v, 32), rdlane_u(v, 48)));
}

// component select from gq[4] (float4 each) for diagonal D (0..15), D literal
#define GX(D)                                                                  \
  ((D) < 4 ? ((D) == 0   ? gq[0].x                                             \
              : (D) == 1 ? gq[0].y                                             \
              : (D) == 2 ? gq[0].z                                             \
                         : gq[0].w)                                            \
   : (D) < 8                                                                   \
       ? ((D) == 4   ? gq[1].x                                                 \
          : (D) == 5 ? gq[1].y                                                 \
          : (D) == 6 ? gq[1].z                                                 \
                     : gq[1].w)                                                \
   : (D) < 12 ? ((D) == 8    ? gq[2].x                                         \
                 : (D) == 9  ? gq[2].y                                         \
                 : (D) == 10 ? gq[2].z                                         \
                             : gq[2].w)                                        \
              : ((D) == 12   ? gq[3].x                                         \
                 : (D) == 13 ? gq[3].y                                         \
                 : (D) == 14 ? gq[3].z                                         \
                             : gq[3].w))

// ---------------- generic 32x32-tile fp32 GEMMs -----------------------------
__global__ __launch_bounds__(256) void gemm_nt(const float* __restrict__ A,
                                               const float* __restrict__ B,
                                               float* __restrict__ C,
                                               int N, int K) {
  __shared__ float As[32][33];
  __shared__ float Bs[32][33];
  int bx = blockIdx.x, by = blockIdx.y;
  int tid = threadIdx.x;
  int tx = tid & 15, ty = tid >> 4;
  float a00 = 0.f, a01 = 0.f, a10 = 0.f, a11 = 0.f;
  for (int k0 = 0; k0 < K; k0 += 32) {
    for (int l = tid; l < 1024; l += 256) {
      int r = l >> 5, c = l & 31;
      As[r][c] = A[(by * 32 + r) * K + k0 + c];
      Bs[r][c] = B[(bx * 32 + r) * K + k0 + c];
    }
    __syncthreads();
#pragma unroll
    for (int k = 0; k < 32; ++k) {
      float x0 = As[2 * ty][k], x1 = As[2 * ty + 1][k];
      float y0 = Bs[2 * tx][k], y1 = Bs[2 * tx + 1][k];
      a00 += x0 * y0; a01 += x0 * y1; a10 += x1 * y0; a11 += x1 * y1;
    }
    __syncthreads();
  }
  int i = by * 32 + 2 * ty, jj = bx * 32 + 2 * tx;
  C[i * N + jj] = a00;           C[i * N + jj + 1] = a01;
  C[(i + 1) * N + jj] = a10;     C[(i + 1) * N + jj + 1] = a11;
}

__global__ __launch_bounds__(256) void gemm_nn(const float* __restrict__ A,
                                               const float* __restrict__ B,
                                               float* __restrict__ C,
                                               int N, int K) {
  __shared__ float As[32][33];
  __shared__ float Bs[32][33];
  int bx = blockIdx.x, by = blockIdx.y;
  int tid = threadIdx.x;
  int tx = tid & 15, ty = tid >> 4;
  float a00 = 0.f, a01 = 0.f, a10 = 0.f, a11 = 0.f;
  for (int k0 = 0; k0 < K; k0 += 32) {
    for (int l = tid; l < 1024; l += 256) {
      int r = l >> 5, c = l & 31;
      As[r][c] = A[(by * 32 + r) * K + k0 + c];
      Bs[r][c] = B[(k0 + r) * N + bx * 32 + c];
    }
    __syncthreads();
#pragma unroll
    for (int k = 0; k < 32; ++k) {
      float x0 = As[2 * ty][k], x1 = As[2 * ty + 1][k];
      float y0 = Bs[k][2 * tx], y1 = Bs[k][2 * tx + 1];
      a00 += x0 * y0; a01 += x0 * y1; a10 += x1 * y0; a11 += x1 * y1;
    }
    __syncthreads();
  }
  int i = by * 32 + 2 * ty, jj = bx * 32 + 2 * tx;
  C[i * N + jj] = a00;           C[i * N + jj + 1] = a01;
  C[(i + 1) * N + jj] = a10;     C[(i + 1) * N + jj + 1] = a11;
}

__global__ __launch_bounds__(256) void final_gemm(const float* __restrict__ G,
                                                  const float* __restrict__ E,
                                                  const float* __restrict__ M0,
                                                  const float* __restrict__ W,
                                                  const float* __restrict__ gS,
                                                  float* __restrict__ out) {
  __shared__ float As[32][33];
  __shared__ float Bs[32][33];
  int bx = blockIdx.x, by = blockIdx.y;
  int tid = threadIdx.x;
  int tx = tid & 15, ty = tid >> 4;
  float a00 = 0.f, a01 = 0.f, a10 = 0.f, a11 = 0.f;
  for (int k0 = 0; k0 < 512; k0 += 32) {
    for (int l = tid; l < 1024; l += 256) {
      int r = l >> 5, c = l & 31;
      As[r][c] = G[(by * 32 + r) * 512 + k0 + c] * W[k0 + c];
      Bs[r][c] = E[(k0 + r) * 384 + bx * 32 + c];
    }
    __syncthreads();
#pragma unroll
    for (int k = 0; k < 32; ++k) {
      float x0 = As[2 * ty][k], x1 = As[2 * ty + 1][k];
      float y0 = Bs[k][2 * tx], y1 = Bs[k][2 * tx + 1];
      a00 += x0 * y0; a01 += x0 * y1; a10 += x1 * y0; a11 += x1 * y1;
    }
    __syncthreads();
  }
  float gv = gS[0];
  int i = by * 32 + 2 * ty, jj = bx * 32 + 2 * tx;
  out[i * 384 + jj]         = gv * M0[i * 384 + jj]         + a00;
  out[i * 384 + jj + 1]     = gv * M0[i * 384 + jj + 1]     + a01;
  out[(i + 1) * 384 + jj]     = gv * M0[(i + 1) * 384 + jj]     + a10;
  out[(i + 1) * 384 + jj + 1] = gv * M0[(i + 1) * 384 + jj + 1] + a11;
}

__global__ __launch_bounds__(256) void prep_kernel(const float* __restrict__ E,
                                                   const float* __restrict__ M0,
                                                   const float* __restrict__ K0,
                                                   float* __restrict__ u,
                                                   float* __restrict__ Kpart) {
  __shared__ double wr[4];
  int b = blockIdx.x;
  int tid = threadIdx.x, lane = tid & 63, wv = tid >> 6;
  if (b < 128) {
    int row = b * 4 + wv;
    const float4* e4 = (const float4*)(E + row * 384);
    const float4* m4 = (const float4*)(M0 + row * 384);
    float p = 0.f;
    for (int i = lane; i < 96; i += 64) {
      float4 a = e4[i], bb = m4[i];
      p += a.x * bb.x + a.y * bb.y + a.z * bb.z + a.w * bb.w;
    }
#pragma unroll
    for (int off = 32; off; off >>= 1) p += __shfl_down(p, off);
    if (lane == 0) u[row] = p;
  } else {
    int cb = b - 128;
    const float* p = K0 + cb * 2304 + tid * 9;
    double acc = 0.0;
#pragma unroll
    for (int i = 0; i < 9; ++i) { double v = (double)p[i]; acc += v * v; }
#pragma unroll
    for (int off = 32; off; off >>= 1) acc += __shfl_down(acc, off);
    if (lane == 0) wr[wv] = acc;
    __syncthreads();
    if (tid == 0) Kpart[cb] = (float)(wr[0] + wr[1] + wr[2] + wr[3]);
  }
}

// ---------------- three-wave scan -------------------------------------------
__global__ __launch_bounds__(192) void scan_kernel(const float* __restrict__ G,
                                                   const float* __restrict__ u,
                                                   const float* __restrict__ Kpart,
                                                   float* __restrict__ Wout,
                                                   float* __restrict__ gOut) {
  __shared__ float RAW[100 * 257];      // 102800 B
  __shared__ float gx_tbl[512 * 16];    // [t][d]: G[t][t+d], d=0..15
  __shared__ float ren_tbl[512];
  __shared__ float u_sh[512];
  __shared__ float wh_sh[512];
  __shared__ float RG_bnew[512];
  __shared__ float RG_nov[512];
  __shared__ int RG_idx[512];
  __shared__ int FLAG;                  // rounds published by wave0
  __shared__ int FLAG2;                 // last round applied to RAW by wave1

  const int tid = threadIdx.x;
  const int wid = tid >> 6;
  const int lane = tid & 63;

  // ---- cooperative init ----
  float4 z4 = {0.f, 0.f, 0.f, 0.f};
  for (int i = tid; i < 6425; i += 192) ((float4*)RAW)[i] = z4;
  for (int tt = tid; tt < 512; tt += 192) {
    const float* gr = G + tt * 512 + tt;
    const int lim = 512 - tt;
#pragma unroll
    for (int d = 0; d < 16; ++d)
      gx_tbl[tt * 16 + d] = (d < lim) ? gr[d] : 0.f;
    ren_tbl[tt] = __builtin_amdgcn_rcpf(__builtin_amdgcn_sqrtf(gr[0]));
  }
  if (tid < 128) ((float4*)u_sh)[tid] = ((const float4*)u)[tid];
  if (tid == 0) { FLAG = 0; FLAG2 = -1; }
  __syncthreads();

  if (wid == 0) {
    // ================== WAVE 0: pure decision chain ==================
    float d0 = 1.f, d1 = 1.f, cn0 = 0.f, cn1 = 0.f, s0 = 0.f, s1 = 0.f;
    int nact = 0;
    float r0[8], r1[8];
#pragma unroll
    for (int j = 0; j < 8; ++j) { r0[j] = 0.f; r1[j] = 0.f; }

    const float4* gx4 = (const float4*)gx_tbl;
    float4 gq[4];
    float renk;
    gq[0] = gx4[0]; gq[1] = gx4[1]; gq[2] = gx4[2]; gq[3] = gx4[3];
    renk = ren_tbl[0];

#define W0STEP(K)                                                              \
    {                                                                          \
      /* prefetch gx/ren for next step (off-chain) */                          \
      const int tnx = (t + (K) + 1 < 512) ? t + (K) + 1 : 511;                 \
      float4 gqn0 = gx4[tnx * 4], gqn1 = gx4[tnx * 4 + 1];                     \
      float4 gqn2 = gx4[tnx * 4 + 2], gqn3 = gx4[tnx * 4 + 3];                 \
      float renn = ren_tbl[tnx];                                               \
      const float trk = gq[0].x;                                               \
      float v0 = (lane < nact) ? s0 * renk * r0[K] : -2.f;                     \
      float v1 = (lane + 64 < nact) ? s1 * renk * r1[K] : -2.f;                \
      unsigned pk0 = (sortable(v0) & ~127u) | (unsigned)(127 - lane);          \
      unsigned pk1 = (sortable(v1) & ~127u) | (unsigned)(63 - lane);           \
      unsigned P = wave_umax64(max(pk0, pk1));                                 \
      int imax = 127 - (int)(P & 127u);                                        \
      float M = unsortable(P & ~127u);                                         \
      float nov = (nact == 0) ? 1.f : fminf(1.f, fmaxf(0.f, 1.f - M * M));     \
      int create = (nov > 0.7f && nact < 100) ? 1 : 0;                         \
      const int idxs = create ? nact : imax;                                   \
      const int cl = idxs & 63, hi = idxs >> 6;                                \
      float dcA = create ? 1.f : 0.95f * d0;                                   \
      float dcB = create ? 1.f : 0.95f * d1;                                   \
      float ccA = create ? trk                                                 \
                         : (0.9025f * cn0 + 0.095f * (d0 * r0[K]) +            \
                            0.0025f * trk);                                    \
      float ccB = create ? trk                                                 \
                         : (0.9025f * cn1 + 0.095f * (d1 * r1[K]) +            \
                            0.0025f * trk);                                    \
      float scA = dcA * __builtin_amdgcn_rcpf(__builtin_amdgcn_sqrtf(ccA));    \
      float scB = dcB * __builtin_amdgcn_rcpf(__builtin_amdgcn_sqrtf(ccB));    \
      float ivA = 0.05f * __builtin_amdgcn_rcpf(dcA);                          \
      float ivB = 0.05f * __builtin_amdgcn_rcpf(dcB);                          \
      bool own0 = (lane == cl) && (hi == 0);                                   \
      bool own1 = (lane == cl) && (hi == 1);                                   \
      d0 = own0 ? dcA : d0; cn0 = own0 ? ccA : cn0; s0 = own0 ? scA : s0;      \
      d1 = own1 ? dcB : d1; cn1 = own1 ? ccB : cn1; s1 = own1 ? scB : s1;      \
      float bnew = create ? 1.f : rdlane_f(hi ? ivB : ivA, cl);                \
      nact += create;                                                          \
      float pb0 = own0 ? bnew : 0.f, pb1 = own1 ? bnew : 0.f;                  \
      _Pragma("unroll") for (int j = (K) + 1; j < 8; ++j) {                    \
        r0[j] += pb0 * GX((j) - (K));                                          \
        r1[j] += pb1 * GX((j) - (K));                                          \
      }                                                                        \
      _Pragma("unroll") for (int j = 0; j < 8; ++j) {                          \
        pa0[j] += pb0 * GX(8 + (j) - (K));                                     \
        pa1[j] += pb1 * GX(8 + (j) - (K));                                     \
      }                                                                        \
      bnewA[K] = bnew; novA[K] = nov; idxA[K] = idxs;                          \
      gq[0] = gqn0; gq[1] = gqn1; gq[2] = gqn2; gq[3] = gqn3;                  \
      renk = renn;                                                             \
    }

    for (int R = 0; R < 64; ++R) {
      const int t = 8 * R;
      const int tn = t + 8;
      const int cnx = tn & 255;

      if (t == 256) {
        // ---- rebuild block 2 from RG journal (steps 0..255) ----
        while (__hip_atomic_load(&FLAG2, __ATOMIC_ACQUIRE,
                                 __HIP_MEMORY_SCOPE_WORKGROUP) < 31)
          __builtin_amdgcn_s_sleep(1);
        for (int i = lane; i < 6425; i += 64) ((float4*)RAW)[i] = z4;
        __builtin_amdgcn_sched_barrier(0);
        const float* Gb = G + 256;
        float A[4][4], Bv[4][4];
        float ab[4], bb[4];
        int ai[4], bi[4];
#pragma unroll
        for (int j = 0; j < 4; ++j) {
#pragma unroll
          for (int m = 0; m < 4; ++m) A[j][m] = Gb[j * 512 + m * 64 + lane];
          ab[j] = RG_bnew[j]; ai[j] = RG_idx[j];
        }
        for (int s = 0; s < 256; s += 8) {
#pragma unroll
          for (int j = 0; j < 4; ++j) {
#pragma unroll
            for (int m = 0; m < 4; ++m)
              Bv[j][m] = Gb[(s + 4 + j) * 512 + m * 64 + lane];
            bb[j] = RG_bnew[s + 4 + j]; bi[j] = RG_idx[s + 4 + j];
          }
#pragma unroll
          for (int j = 0; j < 4; ++j) {
#pragma unroll
            for (int m = 0; m < 4; ++m) {
              const int a_ = ai[j] * 257 + m * 64 + lane;
              RAW[a_] += ab[j] * A[j][m];
            }
          }
          if (s + 8 < 256) {
#pragma unroll
            for (int j = 0; j < 4; ++j) {
#pragma unroll
              for (int m = 0; m < 4; ++m)
                A[j][m] = Gb[(s + 8 + j) * 512 + m * 64 + lane];
              ab[j] = RG_bnew[s + 8 + j]; ai[j] = RG_idx[s + 8 + j];
            }
          }
#pragma unroll
          for (int j = 0; j < 4; ++j) {
#pragma unroll
            for (int m = 0; m < 4; ++m) {
              const int a_ = bi[j] * 257 + m * 64 + lane;
              RAW[a_] += bb[j] * Bv[j][m];
            }
          }
        }
        __builtin_amdgcn_sched_barrier(0);
#pragma unroll
        for (int j = 0; j < 8; ++j) r0[j] = RAW[lane * 257 + j];
        if (lane < 36) {
#pragma unroll
          for (int j = 0; j < 8; ++j) r1[j] = RAW[(lane + 64) * 257 + j];
        }
        __builtin_amdgcn_sched_barrier(0);
      }

      float bnewA[8], novA[8];
      int idxA[8];
      float pa0[8], pa1[8];
#pragma unroll
      for (int j = 0; j < 8; ++j) { pa0[j] = 0.f; pa1[j] = 0.f; }

      W0STEP(0) W0STEP(1) W0STEP(2) W0STEP(3)
      W0STEP(4) W0STEP(5) W0STEP(6) W0STEP(7)

      // end-of-round: read next-round columns (RAW == rounds <= R-1), patch
      if (tn < 512 && cnx != 0) {
        while (__hip_atomic_load(&FLAG2, __ATOMIC_ACQUIRE,
                                 __HIP_MEMORY_SCOPE_WORKGROUP) < R - 1)
          __builtin_amdgcn_s_sleep(1);
        float r0n[8], r1n[8];
#pragma unroll
        for (int j = 0; j < 8; ++j) r0n[j] = RAW[lane * 257 + cnx + j];
        if (lane < 36) {
#pragma unroll
          for (int j = 0; j < 8; ++j) r1n[j] = RAW[(lane + 64) * 257 + cnx + j];
        } else {
#pragma unroll
          for (int j = 0; j < 8; ++j) r1n[j] = 0.f;
        }
#pragma unroll
        for (int j = 0; j < 8; ++j) {
          r0[j] = r0n[j] + pa0[j];
          r1[j] = r1n[j] + pa1[j];
        }
      }
      __builtin_amdgcn_sched_barrier(0);

      // publish (after reads -> wave1 may start applying round R)
      if (lane == 0) {
#pragma unroll
        for (int k = 0; k < 8; ++k) {
          RG_bnew[t + k] = bnewA[k];
          RG_nov[t + k] = novA[k];
          RG_idx[t + k] = idxA[k];
        }
        __hip_atomic_store(&FLAG, R + 1, __ATOMIC_RELEASE,
                           __HIP_MEMORY_SCOPE_WORKGROUP);
      }
    }
#undef W0STEP
  } else if (wid == 1) {
    // ================== WAVE 1: RAW-apply only ==================
    for (int r = 0; r < 64; ++r) {
      const int t = 8 * r;
      const int c = t & 255;
      const int gbase = (t >> 6) & ~3;   // 0 for block1, 4 for block2

      // preload this round's B (only the 4 groups of the current block)
      float B4[8][4];
#pragma unroll
      for (int k = 0; k < 8; ++k)
#pragma unroll
        for (int mg = 0; mg < 4; ++mg)
          B4[k][mg] = G[(t + k) * 512 + (gbase + mg) * 64 + lane];

      while (__hip_atomic_load(&FLAG, __ATOMIC_ACQUIRE,
                               __HIP_MEMORY_SCOPE_WORKGROUP) < r + 1)
        __builtin_amdgcn_s_sleep(1);

      float bn[8];
      int id[8];
#pragma unroll
      for (int k = 0; k < 8; ++k) { bn[k] = RG_bnew[t + k]; id[k] = RG_idx[t + k]; }

#pragma unroll
      for (int k = 0; k < 8; ++k) {
#pragma unroll
        for (int mg = 0; mg < 4; ++mg)
          if (mg * 64 + 63 >= c) {
            const int a_ = id[k] * 257 + mg * 64 + lane;
            RAW[a_] += bn[k] * B4[k][mg];
          }
      }
      __hip_atomic_store(&FLAG2, r, __ATOMIC_RELEASE,
                         __HIP_MEMORY_SCOPE_WORKGROUP);
    }
  } else {
    // ================== WAVE 2: lag chain + q + wh ==================
    float q8[8];
#pragma unroll
    for (int gI = 0; gI < 8; ++gI) q8[gI] = 0.f;
    float n2 = wave_sum64(Kpart[lane]);
    float g = 1.f, ginv = 1.f;

    for (int r = 0; r < 64; ++r) {
      const int t = 8 * r;
      float B[8][8];
#pragma unroll
      for (int k = 0; k < 8; ++k)
#pragma unroll
        for (int gI = 0; gI < 8; ++gI)
          B[k][gI] = G[(t + k) * 512 + gI * 64 + lane];

      while (__hip_atomic_load(&FLAG, __ATOMIC_ACQUIRE,
                               __HIP_MEMORY_SCOPE_WORKGROUP) < r + 1)
        __builtin_amdgcn_s_sleep(1);

      float novv[8];
#pragma unroll
      for (int k = 0; k < 8; ++k) novv[k] = RG_nov[t + k];

      float trm[8], gxw[8][8];
#pragma unroll
      for (int m = 0; m < 8; ++m) {
        trm[m] = gx_tbl[(t + m) * 16];
#pragma unroll
        for (int j = m + 1; j < 8; ++j)
          gxw[m][j] = gx_tbl[(t + m) * 16 + (j - m)];
      }
      float4 uuA = *(const float4*)&u_sh[t];
      float4 uuB = *(const float4*)&u_sh[t + 4];
      float um[8] = {uuA.x, uuA.y, uuA.z, uuA.w, uuB.x, uuB.y, uuB.z, uuB.w};

      const int grp = t >> 6;
      float qsel = q8[0];
#pragma unroll
      for (int gI = 1; gI < 8; ++gI) qsel = (grp == gI) ? q8[gI] : qsel;
      float qeff[8];
#pragma unroll
      for (int k = 0; k < 8; ++k) qeff[k] = rdlane_f(qsel, (t & 63) + k);

      float wh[8];
#pragma unroll
      for (int m = 0; m < 8; ++m) {
        float nov = novv[m];
        float iw = nov * __builtin_amdgcn_sqrtf(nov);
        float psc = 384.0f * __builtin_amdgcn_rcpf(fmaxf(trm[m], 1e-8f));
        float ccf = A_BOOSTF * iw * psc;
        float qv = g * (um[m] + qeff[m]);
        float n2n = n2 + 2.f * ccf * qv + ccf * ccf * trm[m] * trm[m];
        float kn = __builtin_amdgcn_sqrtf(n2n);
        float fct = (kn > 50.f) ? 50.f * __builtin_amdgcn_rcpf(kn) : 1.f;
        float fiv = (kn > 50.f) ? kn * 0.02f : 1.f;
        wh[m] = ccf * ginv;
        n2 = n2n * fct * fct; g *= fct; ginv *= fiv;
#pragma unroll
        for (int j = m + 1; j < 8; ++j)
          qeff[j] += wh[m] * gxw[m][j] * gxw[m][j];
      }

      if (lane == 0) {
#pragma unroll
        for (int m = 0; m < 8; ++m) wh_sh[t + m] = wh[m];
      }
#pragma unroll
      for (int gI = 0; gI < 8; ++gI)
#pragma unroll
        for (int k = 0; k < 8; ++k)
          q8[gI] += wh[k] * B[k][gI] * B[k][gI];
    }

    for (int s2 = lane; s2 < 512; s2 += 64) Wout[s2] = wh_sh[s2] * g;
    if (lane == 0) gOut[0] = g;
  }
}

extern "C" void kernel_launch(void* const* d_in, const int* in_sizes, int n_in,
                              void* d_out, int out_size, void* d_ws,
                              size_t ws_size, hipStream_t stream) {
  const float* E = (const float*)d_in[0];   // [512,384]
  const float* K0 = (const float*)d_in[1];  // [384,384]
  float* out = (float*)d_out;               // [512,384]

  float* G = (float*)d_ws;                  // 512*512
  float* M0 = G + 512 * 512;                // 512*384
  float* u = M0 + 512 * 384;                // 512
  float* W = u + 512;                       // 512
  float* gS = W + 512;                      // 1
  float* Kpart = gS + 1;                    // 64

  gemm_nt<<<dim3(16, 16), 256, 0, stream>>>(E, E, G, 512, 384);     // G = E E^T
  gemm_nn<<<dim3(12, 16), 256, 0, stream>>>(E, K0, M0, 384, 384);   // M0 = E K0
  prep_kernel<<<192, 256, 0, stream>>>(E, M0, K0, u, Kpart);
  scan_kernel<<<1, 192, 0, stream>>>(G, u, Kpart, W, gS);
  final_gemm<<<dim3(12, 16), 256, 0, stream>>>(G, E, M0, W, gS, out);
}